// Round 13
// baseline (32.492 us; speedup 1.0000x reference)
//
#include <hip/hip_runtime.h>
#include <math.h>

#define BS   8192
#define D    1024
#define TPB  256      // 4 waves
#define NBLK 512      // co-resident: <=256 VGPR -> 8 waves/CU -> 2 blocks/CU
#define RPB  16       // rows per block
#define RPWV 4        // rows per wave
#define F4R  4        // float4 per lane per row (D/4/64)
#define NSLOT (NBLK * 4)       // one slot per WAVE (no cross-wave sync pre-poll)
#define SPT   (NSLOT / TPB)    // 8 slots polled per thread

typedef float floatx4 __attribute__((ext_vector_type(4)));
typedef unsigned long long u64;

// R12 + fully-streamed loads. No __syncthreads before the poll:
//  - every thread loads epoch directly (uniform across calls; stream-ordered)
//  - ALL 48 float4 loads issued up front (w first, z,u stream behind)
//  - w2 butterfly waits only on w (partial vmcnt); per-WAVE partial published
//    immediately (2048 slots) while z,u are still in flight
//  - wu/wz reductions + tanh + v-fold consume z,u as they land
//  - poll 8 slots/thread (values ARE the payload; fixed order -> deterministic)
//  - single __syncthreads after the poll for the cross-wave wnrm combine
__global__ __launch_bounds__(TPB, 2) void planar_persistent(
    const float* __restrict__ z, const float* __restrict__ w,
    const float* __restrict__ u, const float* __restrict__ b,
    float* __restrict__ zout, float* __restrict__ ldout,
    u64* __restrict__ slots, unsigned int* __restrict__ epoch)
{
    const int t    = threadIdx.x;
    const int wv   = t >> 6;
    const int l    = t & 63;
    const int row0 = blockIdx.x * RPB + wv * RPWV;

    const unsigned int e1 =
        __hip_atomic_load(epoch, __ATOMIC_RELAXED, __HIP_MEMORY_SCOPE_AGENT)
        + 1u;

    // ---- issue ALL loads up front: w(16), z(16), u(16), b(4) ----
    float4 wr[RPWV][F4R], zv[RPWV][F4R], uv[RPWV][F4R];
#pragma unroll
    for (int r = 0; r < RPWV; ++r) {
        const float4* w4 = (const float4*)w + (size_t)(row0 + r) * (D / 4);
#pragma unroll
        for (int k = 0; k < F4R; ++k) wr[r][k] = w4[l + (k << 6)];
    }
#pragma unroll
    for (int r = 0; r < RPWV; ++r) {
        const float4* z4 = (const float4*)z + (size_t)(row0 + r) * (D / 4);
#pragma unroll
        for (int k = 0; k < F4R; ++k) zv[r][k] = z4[l + (k << 6)];
    }
#pragma unroll
    for (int r = 0; r < RPWV; ++r) {
        const float4* u4 = (const float4*)u + (size_t)(row0 + r) * (D / 4);
#pragma unroll
        for (int k = 0; k < F4R; ++k) uv[r][k] = u4[l + (k << 6)];
    }
    float brow[RPWV];
#pragma unroll
    for (int r = 0; r < RPWV; ++r) brow[r] = b[row0 + r];

    // ---- w2 per row (waits only on w loads), publish per-wave partial ----
    float w2_s[RPWV];
    float w2acc = 0.f;
#pragma unroll
    for (int r = 0; r < RPWV; ++r) {
        float w2 = 0.f;
#pragma unroll
        for (int k = 0; k < F4R; ++k) {
            const float4 a = wr[r][k];
            w2 += a.x*a.x + a.y*a.y + a.z*a.z + a.w*a.w;
        }
#pragma unroll
        for (int off = 32; off > 0; off >>= 1) w2 += __shfl_xor(w2, off, 64);
        w2_s[r] = w2;
        w2acc  += w2;
    }
    if (l == 0) {
        const u64 word = ((u64)e1 << 32) | (u64)__float_as_uint(w2acc);
        __hip_atomic_store(&slots[(blockIdx.x << 2) + wv], word,
                           __ATOMIC_RELAXED, __HIP_MEMORY_SCOPE_AGENT);
    }

    // ---- wu/wz per row; tanh; fold v = z + tnh*u into zv ----
    float wu_s[RPWV], in_s[RPWV], th_s[RPWV];
#pragma unroll
    for (int r = 0; r < RPWV; ++r) {
        float wu = 0.f, wz = 0.f;
#pragma unroll
        for (int k = 0; k < F4R; ++k) {
            const float4 a = wr[r][k];
            wu += a.x*uv[r][k].x + a.y*uv[r][k].y
                + a.z*uv[r][k].z + a.w*uv[r][k].w;
            wz += a.x*zv[r][k].x + a.y*zv[r][k].y
                + a.z*zv[r][k].z + a.w*zv[r][k].w;
        }
#pragma unroll
        for (int off = 32; off > 0; off >>= 1) {
            wu += __shfl_xor(wu, off, 64);
            wz += __shfl_xor(wz, off, 64);
        }
        const float inner = wz + brow[r];
        const float tnh   = tanhf(inner);
#pragma unroll
        for (int k = 0; k < F4R; ++k) {
            zv[r][k].x = fmaf(tnh, uv[r][k].x, zv[r][k].x);
            zv[r][k].y = fmaf(tnh, uv[r][k].y, zv[r][k].y);
            zv[r][k].z = fmaf(tnh, uv[r][k].z, zv[r][k].z);
            zv[r][k].w = fmaf(tnh, uv[r][k].w, zv[r][k].w);
        }
        wu_s[r] = wu; in_s[r] = inner; th_s[r] = tnh;
    }

    // ---- epoch-tag poll barrier (8 slots/thread; no RMW, no acquire) ----
    u64 a[SPT];
    for (;;) {
        bool ok = true;
#pragma unroll
        for (int i = 0; i < SPT; ++i) {
            a[i] = __hip_atomic_load(&slots[t + i * TPB], __ATOMIC_RELAXED,
                                     __HIP_MEMORY_SCOPE_AGENT);
            ok = ok && ((unsigned int)(a[i] >> 32) == e1);
        }
        if (ok) break;
        __builtin_amdgcn_s_sleep(4);
    }
    float gs = 0.f;
#pragma unroll
    for (int i = 0; i < SPT; ++i) gs += __uint_as_float((unsigned int)a[i]);
#pragma unroll
    for (int off = 32; off > 0; off >>= 1) gs += __shfl_xor(gs, off, 64);
    __shared__ float sg[4];
    if (l == 0) sg[wv] = gs;
    __syncthreads();
    const float wnrm = sqrtf(sg[0] + sg[1] + sg[2] + sg[3]);

    // re-arm for next call (barrier passing proves every block read epoch)
    if (blockIdx.x == 0 && t == 0)
        __hip_atomic_store(epoch, e1, __ATOMIC_RELEASE,
                           __HIP_MEMORY_SCOPE_AGENT);

    // ---- finalize from registers (nt stores) ----
#pragma unroll
    for (int r = 0; r < RPWV; ++r) {
        const int   row  = row0 + r;
        const float wu   = wu_s[r];
        const float sp   = (wu > 0.f) ? (wu + log1pf(expf(-wu)))
                                      : log1pf(expf(wu));
        const float coef = (-1.f + sp - wu) / wnrm;
        const float tc   = th_s[r] * coef;
        floatx4* o4 = (floatx4*)zout + (size_t)row * (D / 4);
#pragma unroll
        for (int k = 0; k < F4R; ++k) {
            floatx4 o;
            o.x = fmaf(tc, wr[r][k].x, zv[r][k].x);
            o.y = fmaf(tc, wr[r][k].y, zv[r][k].y);
            o.z = fmaf(tc, wr[r][k].z, zv[r][k].z);
            o.w = fmaf(tc, wr[r][k].w, zv[r][k].w);
            __builtin_nontemporal_store(o, o4 + l + (k << 6));
        }
        if (l == 0) {
            const float s      = fmaf(coef, w2_s[r], wu);
            const float inner2 = fmaf(th_s[r], s, in_s[r]);
            const float th2    = tanhf(inner2);
            const float hp     = 1.f - th2 * th2;
            ldout[row] = logf(fabsf(fmaf(hp, s, 1.f)));
        }
    }
}

extern "C" void kernel_launch(void* const* d_in, const int* in_sizes, int n_in,
                              void* d_out, int out_size, void* d_ws, size_t ws_size,
                              hipStream_t stream) {
    const float* z = (const float*)d_in[0];
    const float* w = (const float*)d_in[1];
    const float* u = (const float*)d_in[2];
    const float* b = (const float*)d_in[3];

    float* out   = (float*)d_out;
    float* zout  = out;                    // [BS, D]
    float* ldout = out + (size_t)BS * D;   // [BS]

    u64*          slots = (u64*)d_ws;                    // [NSLOT] {tag,val}
    unsigned int* epoch = (unsigned int*)(slots + NSLOT); // [1]

    planar_persistent<<<NBLK, TPB, 0, stream>>>(z, w, u, b, zout, ldout,
                                                slots, epoch);
}

// Round 14
// 25.857 us; speedup vs baseline: 1.2566x; 1.2566x over previous
//
#include <hip/hip_runtime.h>
#include <math.h>

#define BS   8192
#define D    1024
#define TPB  256      // 4 waves
#define NBLK 512      // co-resident: <=256 VGPR -> >=2 blocks/CU
#define RPB  16       // rows per block
#define RPWV 4        // rows per wave
#define F4R  4        // float4 per lane per row (D/4/64)
#define SPT  (NBLK / 64)   // per-wave poll: 8 slots per lane

typedef float floatx4 __attribute__((ext_vector_type(4)));
typedef unsigned long long u64;

// R12 + store/load overlap. Per wave: rows {0,1}=batch A, {2,3}=batch B.
//   phase1 : w loads (all 4 rows), w2 butterflies, block publish (epoch-tag)
//   phase2a: z,u loads A; wu/wz butterflies; fold vA = z + tnh*u
//   phase3 : PER-WAVE poll of all 512 slots (8/lane, butterfly) -> wnrm.
//            no __syncthreads after this point (would vmcnt(0)-drain B).
//   phase2b: issue z,u loads B   [pinned below poll by sched_barrier]
//   phase4a: finalize + nt-store A  -- overlaps B's loads in flight
//   phase4b: butterflies/fold/finalize/store B (waitcnt lands here)
__global__ __launch_bounds__(TPB, 2) void planar_persistent(
    const float* __restrict__ z, const float* __restrict__ w,
    const float* __restrict__ u, const float* __restrict__ b,
    float* __restrict__ zout, float* __restrict__ ldout,
    u64* __restrict__ slots, unsigned int* __restrict__ epoch)
{
    const int t    = threadIdx.x;
    const int wv   = t >> 6;
    const int l    = t & 63;
    const int row0 = blockIdx.x * RPB + wv * RPWV;

    const unsigned int e1 =
        __hip_atomic_load(epoch, __ATOMIC_RELAXED, __HIP_MEMORY_SCOPE_AGENT)
        + 1u;

    // ---- phase 1: w loads, per-row w2, block publish ----
    float4 wr[RPWV][F4R];
    float  w2_s[RPWV];
    float  w2acc = 0.f;
#pragma unroll
    for (int r = 0; r < RPWV; ++r) {
        const float4* w4 = (const float4*)w + (size_t)(row0 + r) * (D / 4);
        float w2 = 0.f;
#pragma unroll
        for (int k = 0; k < F4R; ++k) {
            const float4 a = w4[l + (k << 6)];
            wr[r][k] = a;
            w2 += a.x*a.x + a.y*a.y + a.z*a.z + a.w*a.w;
        }
#pragma unroll
        for (int off = 32; off > 0; off >>= 1) w2 += __shfl_xor(w2, off, 64);
        w2_s[r] = w2;
        w2acc  += w2;
    }
    float brow[RPWV];
#pragma unroll
    for (int r = 0; r < RPWV; ++r) brow[r] = b[row0 + r];

    __shared__ float sw[4];
    if (l == 0) sw[wv] = w2acc;
    __syncthreads();                 // only w/b loads outstanding here
    if (t == 0) {
        const float p = sw[0] + sw[1] + sw[2] + sw[3];
        const u64 word = ((u64)e1 << 32) | (u64)__float_as_uint(p);
        __hip_atomic_store(&slots[blockIdx.x], word, __ATOMIC_RELAXED,
                           __HIP_MEMORY_SCOPE_AGENT);
    }

    // ---- phase 2a: batch A (rows 0,1): z,u loads, reduce, fold ----
    float4 va[2][F4R];
    float  wuA[2], inA[2], thA[2];
#pragma unroll
    for (int r = 0; r < 2; ++r) {
        const int row = row0 + r;
        const float4* z4 = (const float4*)z + (size_t)row * (D / 4);
        const float4* u4 = (const float4*)u + (size_t)row * (D / 4);
        float4 zv[F4R], uv[F4R];
#pragma unroll
        for (int k = 0; k < F4R; ++k) {
            zv[k] = z4[l + (k << 6)];
            uv[k] = u4[l + (k << 6)];
        }
        float wu = 0.f, wz = 0.f;
#pragma unroll
        for (int k = 0; k < F4R; ++k) {
            const float4 a = wr[r][k];
            wu += a.x*uv[k].x + a.y*uv[k].y + a.z*uv[k].z + a.w*uv[k].w;
            wz += a.x*zv[k].x + a.y*zv[k].y + a.z*zv[k].z + a.w*zv[k].w;
        }
#pragma unroll
        for (int off = 32; off > 0; off >>= 1) {
            wu += __shfl_xor(wu, off, 64);
            wz += __shfl_xor(wz, off, 64);
        }
        const float inner = wz + brow[r];
        const float tnh   = tanhf(inner);
#pragma unroll
        for (int k = 0; k < F4R; ++k) {
            va[r][k].x = fmaf(tnh, uv[k].x, zv[k].x);
            va[r][k].y = fmaf(tnh, uv[k].y, zv[k].y);
            va[r][k].z = fmaf(tnh, uv[k].z, zv[k].z);
            va[r][k].w = fmaf(tnh, uv[k].w, zv[k].w);
        }
        wuA[r] = wu; inA[r] = inner; thA[r] = tnh;
    }

    // ---- phase 3: per-wave epoch-tag poll (no syncthreads after) ----
    u64 a[SPT];
    for (;;) {
        bool ok = true;
#pragma unroll
        for (int i = 0; i < SPT; ++i) {
            a[i] = __hip_atomic_load(&slots[l + (i << 6)], __ATOMIC_RELAXED,
                                     __HIP_MEMORY_SCOPE_AGENT);
            ok = ok && ((unsigned int)(a[i] >> 32) == e1);
        }
        if (__all(ok)) break;
        __builtin_amdgcn_s_sleep(4);
    }
    float gs = 0.f;
#pragma unroll
    for (int i = 0; i < SPT; ++i) gs += __uint_as_float((unsigned int)a[i]);
#pragma unroll
    for (int off = 32; off > 0; off >>= 1) gs += __shfl_xor(gs, off, 64);
    const float wnrm = sqrtf(gs);

    if (blockIdx.x == 0 && t == 0)
        __hip_atomic_store(epoch, e1, __ATOMIC_RELEASE,
                           __HIP_MEMORY_SCOPE_AGENT);

    __builtin_amdgcn_sched_barrier(0);   // B loads stay BELOW the poll

    // ---- phase 2b: issue batch B (rows 2,3) z,u loads ----
    float4 zB[2][F4R], uB[2][F4R];
#pragma unroll
    for (int r = 0; r < 2; ++r) {
        const int row = row0 + 2 + r;
        const float4* z4 = (const float4*)z + (size_t)row * (D / 4);
        const float4* u4 = (const float4*)u + (size_t)row * (D / 4);
#pragma unroll
        for (int k = 0; k < F4R; ++k) {
            zB[r][k] = z4[l + (k << 6)];
            uB[r][k] = u4[l + (k << 6)];
        }
    }

    __builtin_amdgcn_sched_barrier(0);   // stores stay BELOW the B issues

    // ---- phase 4a: finalize + store batch A (overlaps B loads) ----
#pragma unroll
    for (int r = 0; r < 2; ++r) {
        const int   row  = row0 + r;
        const float wu   = wuA[r];
        const float sp   = (wu > 0.f) ? (wu + log1pf(expf(-wu)))
                                      : log1pf(expf(wu));
        const float coef = (-1.f + sp - wu) / wnrm;
        const float tc   = thA[r] * coef;
        floatx4* o4 = (floatx4*)zout + (size_t)row * (D / 4);
#pragma unroll
        for (int k = 0; k < F4R; ++k) {
            floatx4 o;
            o.x = fmaf(tc, wr[r][k].x, va[r][k].x);
            o.y = fmaf(tc, wr[r][k].y, va[r][k].y);
            o.z = fmaf(tc, wr[r][k].z, va[r][k].z);
            o.w = fmaf(tc, wr[r][k].w, va[r][k].w);
            __builtin_nontemporal_store(o, o4 + l + (k << 6));
        }
        if (l == 0) {
            const float s      = fmaf(coef, w2_s[r], wu);
            const float inner2 = fmaf(thA[r], s, inA[r]);
            const float th2    = tanhf(inner2);
            const float hp     = 1.f - th2 * th2;
            ldout[row] = logf(fabsf(fmaf(hp, s, 1.f)));
        }
    }

    // ---- phase 4b: reduce + finalize + store batch B ----
#pragma unroll
    for (int r = 0; r < 2; ++r) {
        const int rr  = 2 + r;
        const int row = row0 + rr;
        float wu = 0.f, wz = 0.f;
#pragma unroll
        for (int k = 0; k < F4R; ++k) {
            const float4 aa = wr[rr][k];
            wu += aa.x*uB[r][k].x + aa.y*uB[r][k].y
                + aa.z*uB[r][k].z + aa.w*uB[r][k].w;
            wz += aa.x*zB[r][k].x + aa.y*zB[r][k].y
                + aa.z*zB[r][k].z + aa.w*zB[r][k].w;
        }
#pragma unroll
        for (int off = 32; off > 0; off >>= 1) {
            wu += __shfl_xor(wu, off, 64);
            wz += __shfl_xor(wz, off, 64);
        }
        const float inner = wz + brow[rr];
        const float tnh   = tanhf(inner);
        const float sp    = (wu > 0.f) ? (wu + log1pf(expf(-wu)))
                                       : log1pf(expf(wu));
        const float coef  = (-1.f + sp - wu) / wnrm;
        const float tc    = tnh * coef;
        floatx4* o4 = (floatx4*)zout + (size_t)row * (D / 4);
#pragma unroll
        for (int k = 0; k < F4R; ++k) {
            floatx4 o;
            o.x = fmaf(tc, wr[rr][k].x, fmaf(tnh, uB[r][k].x, zB[r][k].x));
            o.y = fmaf(tc, wr[rr][k].y, fmaf(tnh, uB[r][k].y, zB[r][k].y));
            o.z = fmaf(tc, wr[rr][k].z, fmaf(tnh, uB[r][k].z, zB[r][k].z));
            o.w = fmaf(tc, wr[rr][k].w, fmaf(tnh, uB[r][k].w, zB[r][k].w));
            __builtin_nontemporal_store(o, o4 + l + (k << 6));
        }
        if (l == 0) {
            const float s      = fmaf(coef, w2_s[rr], wu);
            const float inner2 = fmaf(tnh, s, inner);
            const float th2    = tanhf(inner2);
            const float hp     = 1.f - th2 * th2;
            ldout[row] = logf(fabsf(fmaf(hp, s, 1.f)));
        }
    }
}

extern "C" void kernel_launch(void* const* d_in, const int* in_sizes, int n_in,
                              void* d_out, int out_size, void* d_ws, size_t ws_size,
                              hipStream_t stream) {
    const float* z = (const float*)d_in[0];
    const float* w = (const float*)d_in[1];
    const float* u = (const float*)d_in[2];
    const float* b = (const float*)d_in[3];

    float* out   = (float*)d_out;
    float* zout  = out;                    // [BS, D]
    float* ldout = out + (size_t)BS * D;   // [BS]

    u64*          slots = (u64*)d_ws;                    // [NBLK] {tag,val}
    unsigned int* epoch = (unsigned int*)(slots + NBLK); // [1]

    planar_persistent<<<NBLK, TPB, 0, stream>>>(z, w, u, b, zout, ldout,
                                                slots, epoch);
}

// Round 15
// 25.323 us; speedup vs baseline: 1.2831x; 1.0211x over previous
//
#include <hip/hip_runtime.h>
#include <math.h>

#define BS   8192
#define D    1024
#define NBLK 512      // block count (both variants); barrier population
#define RPB  16       // rows per block
#define F4R  4        // float4 per lane per row (D/4/64)

typedef float floatx4 __attribute__((ext_vector_type(4)));
typedef unsigned long long u64;

// ---------------------------------------------------------------------------
// Variant A (preferred): 512 threads = 8 waves/block, 2 rows/wave.
// 2 blocks/CU -> 16 waves/CU (vs R12's 8): doubled outstanding loads.
// Same epoch-tagged, RMW-free, acquire-free sentinel barrier as R12.
// ---------------------------------------------------------------------------
__global__ __launch_bounds__(512, 4) void planar512(
    const float* __restrict__ z, const float* __restrict__ w,
    const float* __restrict__ u, const float* __restrict__ b,
    float* __restrict__ zout, float* __restrict__ ldout,
    u64* __restrict__ slots, unsigned int* __restrict__ epoch)
{
    const int t    = threadIdx.x;
    const int wv   = t >> 6;          // 0..7
    const int l    = t & 63;
    const int row0 = blockIdx.x * RPB + wv * 2;

    const unsigned int e1 =
        __hip_atomic_load(epoch, __ATOMIC_RELAXED, __HIP_MEMORY_SCOPE_AGENT)
        + 1u;

    // ---- phase 1: w loads (2 rows), per-row w2, block publish ----
    float4 wr[2][F4R];
    float  w2_s[2];
    float  w2acc = 0.f;
#pragma unroll
    for (int r = 0; r < 2; ++r) {
        const float4* w4 = (const float4*)w + (size_t)(row0 + r) * (D / 4);
        float w2 = 0.f;
#pragma unroll
        for (int k = 0; k < F4R; ++k) {
            const float4 a = w4[l + (k << 6)];
            wr[r][k] = a;
            w2 += a.x*a.x + a.y*a.y + a.z*a.z + a.w*a.w;
        }
#pragma unroll
        for (int off = 32; off > 0; off >>= 1) w2 += __shfl_xor(w2, off, 64);
        w2_s[r] = w2;
        w2acc  += w2;
    }
    float brow[2];
#pragma unroll
    for (int r = 0; r < 2; ++r) brow[r] = b[row0 + r];

    __shared__ float sw[8], sg[8];
    if (l == 0) sw[wv] = w2acc;
    __syncthreads();                  // only w/b loads outstanding
    if (t == 0) {
        float p = 0.f;
#pragma unroll
        for (int i = 0; i < 8; ++i) p += sw[i];
        const u64 word = ((u64)e1 << 32) | (u64)__float_as_uint(p);
        __hip_atomic_store(&slots[blockIdx.x], word, __ATOMIC_RELAXED,
                           __HIP_MEMORY_SCOPE_AGENT);
    }

    // ---- phase 2: z,u loads, wu/wz butterflies, fold v = z + tnh*u ----
    float4 vr[2][F4R];
    float  wu_s[2], in_s[2], th_s[2];
#pragma unroll
    for (int r = 0; r < 2; ++r) {
        const int row = row0 + r;
        const float4* z4 = (const float4*)z + (size_t)row * (D / 4);
        const float4* u4 = (const float4*)u + (size_t)row * (D / 4);
        float4 zv[F4R], uv[F4R];
#pragma unroll
        for (int k = 0; k < F4R; ++k) {
            zv[k] = z4[l + (k << 6)];
            uv[k] = u4[l + (k << 6)];
        }
        float wu = 0.f, wz = 0.f;
#pragma unroll
        for (int k = 0; k < F4R; ++k) {
            const float4 a = wr[r][k];
            wu += a.x*uv[k].x + a.y*uv[k].y + a.z*uv[k].z + a.w*uv[k].w;
            wz += a.x*zv[k].x + a.y*zv[k].y + a.z*zv[k].z + a.w*zv[k].w;
        }
#pragma unroll
        for (int off = 32; off > 0; off >>= 1) {
            wu += __shfl_xor(wu, off, 64);
            wz += __shfl_xor(wz, off, 64);
        }
        const float inner = wz + brow[r];
        const float tnh   = tanhf(inner);
#pragma unroll
        for (int k = 0; k < F4R; ++k) {
            vr[r][k].x = fmaf(tnh, uv[k].x, zv[k].x);
            vr[r][k].y = fmaf(tnh, uv[k].y, zv[k].y);
            vr[r][k].z = fmaf(tnh, uv[k].z, zv[k].z);
            vr[r][k].w = fmaf(tnh, uv[k].w, zv[k].w);
        }
        wu_s[r] = wu; in_s[r] = inner; th_s[r] = tnh;
    }

    // ---- phase 3: epoch-tag poll (1 slot/thread), fixed-order reduce ----
    u64 a0;
    for (;;) {
        a0 = __hip_atomic_load(&slots[t], __ATOMIC_RELAXED,
                               __HIP_MEMORY_SCOPE_AGENT);
        if ((unsigned int)(a0 >> 32) == e1) break;
        __builtin_amdgcn_s_sleep(4);
    }
    float gs = __uint_as_float((unsigned int)a0);
#pragma unroll
    for (int off = 32; off > 0; off >>= 1) gs += __shfl_xor(gs, off, 64);
    if (l == 0) sg[wv] = gs;
    __syncthreads();
    float gw2 = 0.f;
#pragma unroll
    for (int i = 0; i < 8; ++i) gw2 += sg[i];
    const float wnrm = sqrtf(gw2);

    if (blockIdx.x == 0 && t == 0)
        __hip_atomic_store(epoch, e1, __ATOMIC_RELEASE,
                           __HIP_MEMORY_SCOPE_AGENT);

    // ---- phase 4: finalize from registers (nt stores) ----
#pragma unroll
    for (int r = 0; r < 2; ++r) {
        const int   row  = row0 + r;
        const float wu   = wu_s[r];
        const float sp   = (wu > 0.f) ? (wu + log1pf(expf(-wu)))
                                      : log1pf(expf(wu));
        const float coef = (-1.f + sp - wu) / wnrm;
        const float tc   = th_s[r] * coef;
        floatx4* o4 = (floatx4*)zout + (size_t)row * (D / 4);
#pragma unroll
        for (int k = 0; k < F4R; ++k) {
            floatx4 o;
            o.x = fmaf(tc, wr[r][k].x, vr[r][k].x);
            o.y = fmaf(tc, wr[r][k].y, vr[r][k].y);
            o.z = fmaf(tc, wr[r][k].z, vr[r][k].z);
            o.w = fmaf(tc, wr[r][k].w, vr[r][k].w);
            __builtin_nontemporal_store(o, o4 + l + (k << 6));
        }
        if (l == 0) {
            const float s      = fmaf(coef, w2_s[r], wu);
            const float inner2 = fmaf(th_s[r], s, in_s[r]);
            const float th2    = tanhf(inner2);
            const float hp     = 1.f - th2 * th2;
            ldout[row] = logf(fabsf(fmaf(hp, s, 1.f)));
        }
    }
}

// ---------------------------------------------------------------------------
// Variant B (fallback): exact R12 kernel — 256 threads, 4 rows/wave.
// ---------------------------------------------------------------------------
__global__ __launch_bounds__(256, 2) void planar256(
    const float* __restrict__ z, const float* __restrict__ w,
    const float* __restrict__ u, const float* __restrict__ b,
    float* __restrict__ zout, float* __restrict__ ldout,
    u64* __restrict__ slots, unsigned int* __restrict__ epoch)
{
    const int t    = threadIdx.x;
    const int wv   = t >> 6;
    const int l    = t & 63;
    const int row0 = blockIdx.x * RPB + wv * 4;

    __shared__ unsigned int s_e;
    __shared__ float sw[4], sg[4];
    if (t == 0)
        s_e = __hip_atomic_load(epoch, __ATOMIC_RELAXED,
                                __HIP_MEMORY_SCOPE_AGENT);

    float4 wr[4][F4R];
    float  w2_s[4];
    float  w2acc = 0.f;
#pragma unroll
    for (int r = 0; r < 4; ++r) {
        const float4* w4 = (const float4*)w + (size_t)(row0 + r) * (D / 4);
        float w2 = 0.f;
#pragma unroll
        for (int k = 0; k < F4R; ++k) {
            const float4 a = w4[l + (k << 6)];
            wr[r][k] = a;
            w2 += a.x*a.x + a.y*a.y + a.z*a.z + a.w*a.w;
        }
#pragma unroll
        for (int off = 32; off > 0; off >>= 1) w2 += __shfl_xor(w2, off, 64);
        w2_s[r] = w2;
        w2acc  += w2;
    }
    if (l == 0) sw[wv] = w2acc;
    __syncthreads();
    const unsigned int e1 = s_e + 1u;
    if (t == 0) {
        const float p = sw[0] + sw[1] + sw[2] + sw[3];
        const u64 word = ((u64)e1 << 32) | (u64)__float_as_uint(p);
        __hip_atomic_store(&slots[blockIdx.x], word, __ATOMIC_RELAXED,
                           __HIP_MEMORY_SCOPE_AGENT);
    }

    float4 vr[4][F4R];
    float  wu_s[4], in_s[4], th_s[4];
#pragma unroll
    for (int r = 0; r < 4; ++r) {
        const int row = row0 + r;
        const float4* z4 = (const float4*)z + (size_t)row * (D / 4);
        const float4* u4 = (const float4*)u + (size_t)row * (D / 4);
        float4 zv[F4R], uv[F4R];
#pragma unroll
        for (int k = 0; k < F4R; ++k) {
            zv[k] = z4[l + (k << 6)];
            uv[k] = u4[l + (k << 6)];
        }
        float wu = 0.f, wz = 0.f;
#pragma unroll
        for (int k = 0; k < F4R; ++k) {
            const float4 a = wr[r][k];
            wu += a.x*uv[k].x + a.y*uv[k].y + a.z*uv[k].z + a.w*uv[k].w;
            wz += a.x*zv[k].x + a.y*zv[k].y + a.z*zv[k].z + a.w*zv[k].w;
        }
#pragma unroll
        for (int off = 32; off > 0; off >>= 1) {
            wu += __shfl_xor(wu, off, 64);
            wz += __shfl_xor(wz, off, 64);
        }
        const float inner = wz + b[row];
        const float tnh   = tanhf(inner);
#pragma unroll
        for (int k = 0; k < F4R; ++k) {
            vr[r][k].x = fmaf(tnh, uv[k].x, zv[k].x);
            vr[r][k].y = fmaf(tnh, uv[k].y, zv[k].y);
            vr[r][k].z = fmaf(tnh, uv[k].z, zv[k].z);
            vr[r][k].w = fmaf(tnh, uv[k].w, zv[k].w);
        }
        wu_s[r] = wu; in_s[r] = inner; th_s[r] = tnh;
    }

    u64 a0, a1;
    for (;;) {
        a0 = __hip_atomic_load(&slots[t], __ATOMIC_RELAXED,
                               __HIP_MEMORY_SCOPE_AGENT);
        a1 = __hip_atomic_load(&slots[t + 256], __ATOMIC_RELAXED,
                               __HIP_MEMORY_SCOPE_AGENT);
        if ((unsigned int)(a0 >> 32) == e1 &&
            (unsigned int)(a1 >> 32) == e1) break;
        __builtin_amdgcn_s_sleep(4);
    }
    float gs = __uint_as_float((unsigned int)a0)
             + __uint_as_float((unsigned int)a1);
#pragma unroll
    for (int off = 32; off > 0; off >>= 1) gs += __shfl_xor(gs, off, 64);
    if (l == 0) sg[wv] = gs;
    __syncthreads();
    const float wnrm = sqrtf(sg[0] + sg[1] + sg[2] + sg[3]);

    if (blockIdx.x == 0 && t == 0)
        __hip_atomic_store(epoch, e1, __ATOMIC_RELEASE,
                           __HIP_MEMORY_SCOPE_AGENT);

#pragma unroll
    for (int r = 0; r < 4; ++r) {
        const int   row  = row0 + r;
        const float wu   = wu_s[r];
        const float sp   = (wu > 0.f) ? (wu + log1pf(expf(-wu)))
                                      : log1pf(expf(wu));
        const float coef = (-1.f + sp - wu) / wnrm;
        const float tc   = th_s[r] * coef;
        floatx4* o4 = (floatx4*)zout + (size_t)row * (D / 4);
#pragma unroll
        for (int k = 0; k < F4R; ++k) {
            floatx4 o;
            o.x = fmaf(tc, wr[r][k].x, vr[r][k].x);
            o.y = fmaf(tc, wr[r][k].y, vr[r][k].y);
            o.z = fmaf(tc, wr[r][k].z, vr[r][k].z);
            o.w = fmaf(tc, wr[r][k].w, vr[r][k].w);
            __builtin_nontemporal_store(o, o4 + l + (k << 6));
        }
        if (l == 0) {
            const float s      = fmaf(coef, w2_s[r], wu);
            const float inner2 = fmaf(th_s[r], s, in_s[r]);
            const float th2    = tanhf(inner2);
            const float hp     = 1.f - th2 * th2;
            ldout[row] = logf(fabsf(fmaf(hp, s, 1.f)));
        }
    }
}

extern "C" void kernel_launch(void* const* d_in, const int* in_sizes, int n_in,
                              void* d_out, int out_size, void* d_ws, size_t ws_size,
                              hipStream_t stream) {
    const float* z = (const float*)d_in[0];
    const float* w = (const float*)d_in[1];
    const float* u = (const float*)d_in[2];
    const float* b = (const float*)d_in[3];

    float* out   = (float*)d_out;
    float* zout  = out;                    // [BS, D]
    float* ldout = out + (size_t)BS * D;   // [BS]

    u64*          slots = (u64*)d_ws;                    // [NBLK] {tag,val}
    unsigned int* epoch = (unsigned int*)(slots + NBLK); // [1]

    // Deterministic host-side occupancy gate (capture-safe query): the
    // 512-thread variant needs 2 blocks/CU co-resident for its barrier.
    int nb2 = 0;
    hipError_t err =
        hipOccupancyMaxActiveBlocksPerMultiprocessor(&nb2, planar512, 512, 0);
    if (err == hipSuccess && nb2 >= 2) {
        planar512<<<NBLK, 512, 0, stream>>>(z, w, u, b, zout, ldout,
                                            slots, epoch);
    } else {
        planar256<<<NBLK, 256, 0, stream>>>(z, w, u, b, zout, ldout,
                                            slots, epoch);
    }
}

// Round 16
// 24.961 us; speedup vs baseline: 1.3017x; 1.0145x over previous
//
#include <hip/hip_runtime.h>
#include <math.h>

#define BS   8192
#define D    1024
#define NBLK 512      // block count (both variants); barrier population
#define RPB  16       // rows per block
#define F4R  4        // float4 per lane per row (D/4/64)

typedef float floatx4 __attribute__((ext_vector_type(4)));
typedef unsigned long long u64;

// ---------------------------------------------------------------------------
// Variant A (preferred): 512 threads = 8 waves/block, 2 rows/wave.
// 2 blocks/CU -> 16 waves/CU (vs R12's 8): doubled outstanding loads.
// Same epoch-tagged, RMW-free, acquire-free sentinel barrier as R12.
// ---------------------------------------------------------------------------
__global__ __launch_bounds__(512, 4) void planar512(
    const float* __restrict__ z, const float* __restrict__ w,
    const float* __restrict__ u, const float* __restrict__ b,
    float* __restrict__ zout, float* __restrict__ ldout,
    u64* __restrict__ slots, unsigned int* __restrict__ epoch)
{
    const int t    = threadIdx.x;
    const int wv   = t >> 6;          // 0..7
    const int l    = t & 63;
    const int row0 = blockIdx.x * RPB + wv * 2;

    const unsigned int e1 =
        __hip_atomic_load(epoch, __ATOMIC_RELAXED, __HIP_MEMORY_SCOPE_AGENT)
        + 1u;

    // ---- phase 1: w loads (2 rows), per-row w2, block publish ----
    float4 wr[2][F4R];
    float  w2_s[2];
    float  w2acc = 0.f;
#pragma unroll
    for (int r = 0; r < 2; ++r) {
        const float4* w4 = (const float4*)w + (size_t)(row0 + r) * (D / 4);
        float w2 = 0.f;
#pragma unroll
        for (int k = 0; k < F4R; ++k) {
            const float4 a = w4[l + (k << 6)];
            wr[r][k] = a;
            w2 += a.x*a.x + a.y*a.y + a.z*a.z + a.w*a.w;
        }
#pragma unroll
        for (int off = 32; off > 0; off >>= 1) w2 += __shfl_xor(w2, off, 64);
        w2_s[r] = w2;
        w2acc  += w2;
    }
    float brow[2];
#pragma unroll
    for (int r = 0; r < 2; ++r) brow[r] = b[row0 + r];

    __shared__ float sw[8], sg[8];
    if (l == 0) sw[wv] = w2acc;
    __syncthreads();                  // only w/b loads outstanding
    if (t == 0) {
        float p = 0.f;
#pragma unroll
        for (int i = 0; i < 8; ++i) p += sw[i];
        const u64 word = ((u64)e1 << 32) | (u64)__float_as_uint(p);
        __hip_atomic_store(&slots[blockIdx.x], word, __ATOMIC_RELAXED,
                           __HIP_MEMORY_SCOPE_AGENT);
    }

    // ---- phase 2: z,u loads, wu/wz butterflies, fold v = z + tnh*u ----
    float4 vr[2][F4R];
    float  wu_s[2], in_s[2], th_s[2];
#pragma unroll
    for (int r = 0; r < 2; ++r) {
        const int row = row0 + r;
        const float4* z4 = (const float4*)z + (size_t)row * (D / 4);
        const float4* u4 = (const float4*)u + (size_t)row * (D / 4);
        float4 zv[F4R], uv[F4R];
#pragma unroll
        for (int k = 0; k < F4R; ++k) {
            zv[k] = z4[l + (k << 6)];
            uv[k] = u4[l + (k << 6)];
        }
        float wu = 0.f, wz = 0.f;
#pragma unroll
        for (int k = 0; k < F4R; ++k) {
            const float4 a = wr[r][k];
            wu += a.x*uv[k].x + a.y*uv[k].y + a.z*uv[k].z + a.w*uv[k].w;
            wz += a.x*zv[k].x + a.y*zv[k].y + a.z*zv[k].z + a.w*zv[k].w;
        }
#pragma unroll
        for (int off = 32; off > 0; off >>= 1) {
            wu += __shfl_xor(wu, off, 64);
            wz += __shfl_xor(wz, off, 64);
        }
        const float inner = wz + brow[r];
        const float tnh   = tanhf(inner);
#pragma unroll
        for (int k = 0; k < F4R; ++k) {
            vr[r][k].x = fmaf(tnh, uv[k].x, zv[k].x);
            vr[r][k].y = fmaf(tnh, uv[k].y, zv[k].y);
            vr[r][k].z = fmaf(tnh, uv[k].z, zv[k].z);
            vr[r][k].w = fmaf(tnh, uv[k].w, zv[k].w);
        }
        wu_s[r] = wu; in_s[r] = inner; th_s[r] = tnh;
    }

    // ---- phase 3: epoch-tag poll (1 slot/thread), fixed-order reduce ----
    u64 a0;
    for (;;) {
        a0 = __hip_atomic_load(&slots[t], __ATOMIC_RELAXED,
                               __HIP_MEMORY_SCOPE_AGENT);
        if ((unsigned int)(a0 >> 32) == e1) break;
        __builtin_amdgcn_s_sleep(4);
    }
    float gs = __uint_as_float((unsigned int)a0);
#pragma unroll
    for (int off = 32; off > 0; off >>= 1) gs += __shfl_xor(gs, off, 64);
    if (l == 0) sg[wv] = gs;
    __syncthreads();
    float gw2 = 0.f;
#pragma unroll
    for (int i = 0; i < 8; ++i) gw2 += sg[i];
    const float wnrm = sqrtf(gw2);

    if (blockIdx.x == 0 && t == 0)
        __hip_atomic_store(epoch, e1, __ATOMIC_RELEASE,
                           __HIP_MEMORY_SCOPE_AGENT);

    // ---- phase 4: finalize from registers (nt stores) ----
#pragma unroll
    for (int r = 0; r < 2; ++r) {
        const int   row  = row0 + r;
        const float wu   = wu_s[r];
        const float sp   = (wu > 0.f) ? (wu + log1pf(expf(-wu)))
                                      : log1pf(expf(wu));
        const float coef = (-1.f + sp - wu) / wnrm;
        const float tc   = th_s[r] * coef;
        floatx4* o4 = (floatx4*)zout + (size_t)row * (D / 4);
#pragma unroll
        for (int k = 0; k < F4R; ++k) {
            floatx4 o;
            o.x = fmaf(tc, wr[r][k].x, vr[r][k].x);
            o.y = fmaf(tc, wr[r][k].y, vr[r][k].y);
            o.z = fmaf(tc, wr[r][k].z, vr[r][k].z);
            o.w = fmaf(tc, wr[r][k].w, vr[r][k].w);
            __builtin_nontemporal_store(o, o4 + l + (k << 6));
        }
        if (l == 0) {
            const float s      = fmaf(coef, w2_s[r], wu);
            const float inner2 = fmaf(th_s[r], s, in_s[r]);
            const float th2    = tanhf(inner2);
            const float hp     = 1.f - th2 * th2;
            ldout[row] = logf(fabsf(fmaf(hp, s, 1.f)));
        }
    }
}

// ---------------------------------------------------------------------------
// Variant B (fallback): exact R12 kernel — 256 threads, 4 rows/wave.
// ---------------------------------------------------------------------------
__global__ __launch_bounds__(256, 2) void planar256(
    const float* __restrict__ z, const float* __restrict__ w,
    const float* __restrict__ u, const float* __restrict__ b,
    float* __restrict__ zout, float* __restrict__ ldout,
    u64* __restrict__ slots, unsigned int* __restrict__ epoch)
{
    const int t    = threadIdx.x;
    const int wv   = t >> 6;
    const int l    = t & 63;
    const int row0 = blockIdx.x * RPB + wv * 4;

    __shared__ unsigned int s_e;
    __shared__ float sw[4], sg[4];
    if (t == 0)
        s_e = __hip_atomic_load(epoch, __ATOMIC_RELAXED,
                                __HIP_MEMORY_SCOPE_AGENT);

    float4 wr[4][F4R];
    float  w2_s[4];
    float  w2acc = 0.f;
#pragma unroll
    for (int r = 0; r < 4; ++r) {
        const float4* w4 = (const float4*)w + (size_t)(row0 + r) * (D / 4);
        float w2 = 0.f;
#pragma unroll
        for (int k = 0; k < F4R; ++k) {
            const float4 a = w4[l + (k << 6)];
            wr[r][k] = a;
            w2 += a.x*a.x + a.y*a.y + a.z*a.z + a.w*a.w;
        }
#pragma unroll
        for (int off = 32; off > 0; off >>= 1) w2 += __shfl_xor(w2, off, 64);
        w2_s[r] = w2;
        w2acc  += w2;
    }
    if (l == 0) sw[wv] = w2acc;
    __syncthreads();
    const unsigned int e1 = s_e + 1u;
    if (t == 0) {
        const float p = sw[0] + sw[1] + sw[2] + sw[3];
        const u64 word = ((u64)e1 << 32) | (u64)__float_as_uint(p);
        __hip_atomic_store(&slots[blockIdx.x], word, __ATOMIC_RELAXED,
                           __HIP_MEMORY_SCOPE_AGENT);
    }

    float4 vr[4][F4R];
    float  wu_s[4], in_s[4], th_s[4];
#pragma unroll
    for (int r = 0; r < 4; ++r) {
        const int row = row0 + r;
        const float4* z4 = (const float4*)z + (size_t)row * (D / 4);
        const float4* u4 = (const float4*)u + (size_t)row * (D / 4);
        float4 zv[F4R], uv[F4R];
#pragma unroll
        for (int k = 0; k < F4R; ++k) {
            zv[k] = z4[l + (k << 6)];
            uv[k] = u4[l + (k << 6)];
        }
        float wu = 0.f, wz = 0.f;
#pragma unroll
        for (int k = 0; k < F4R; ++k) {
            const float4 a = wr[r][k];
            wu += a.x*uv[k].x + a.y*uv[k].y + a.z*uv[k].z + a.w*uv[k].w;
            wz += a.x*zv[k].x + a.y*zv[k].y + a.z*zv[k].z + a.w*zv[k].w;
        }
#pragma unroll
        for (int off = 32; off > 0; off >>= 1) {
            wu += __shfl_xor(wu, off, 64);
            wz += __shfl_xor(wz, off, 64);
        }
        const float inner = wz + b[row];
        const float tnh   = tanhf(inner);
#pragma unroll
        for (int k = 0; k < F4R; ++k) {
            vr[r][k].x = fmaf(tnh, uv[k].x, zv[k].x);
            vr[r][k].y = fmaf(tnh, uv[k].y, zv[k].y);
            vr[r][k].z = fmaf(tnh, uv[k].z, zv[k].z);
            vr[r][k].w = fmaf(tnh, uv[k].w, zv[k].w);
        }
        wu_s[r] = wu; in_s[r] = inner; th_s[r] = tnh;
    }

    u64 a0, a1;
    for (;;) {
        a0 = __hip_atomic_load(&slots[t], __ATOMIC_RELAXED,
                               __HIP_MEMORY_SCOPE_AGENT);
        a1 = __hip_atomic_load(&slots[t + 256], __ATOMIC_RELAXED,
                               __HIP_MEMORY_SCOPE_AGENT);
        if ((unsigned int)(a0 >> 32) == e1 &&
            (unsigned int)(a1 >> 32) == e1) break;
        __builtin_amdgcn_s_sleep(4);
    }
    float gs = __uint_as_float((unsigned int)a0)
             + __uint_as_float((unsigned int)a1);
#pragma unroll
    for (int off = 32; off > 0; off >>= 1) gs += __shfl_xor(gs, off, 64);
    if (l == 0) sg[wv] = gs;
    __syncthreads();
    const float wnrm = sqrtf(sg[0] + sg[1] + sg[2] + sg[3]);

    if (blockIdx.x == 0 && t == 0)
        __hip_atomic_store(epoch, e1, __ATOMIC_RELEASE,
                           __HIP_MEMORY_SCOPE_AGENT);

#pragma unroll
    for (int r = 0; r < 4; ++r) {
        const int   row  = row0 + r;
        const float wu   = wu_s[r];
        const float sp   = (wu > 0.f) ? (wu + log1pf(expf(-wu)))
                                      : log1pf(expf(wu));
        const float coef = (-1.f + sp - wu) / wnrm;
        const float tc   = th_s[r] * coef;
        floatx4* o4 = (floatx4*)zout + (size_t)row * (D / 4);
#pragma unroll
        for (int k = 0; k < F4R; ++k) {
            floatx4 o;
            o.x = fmaf(tc, wr[r][k].x, vr[r][k].x);
            o.y = fmaf(tc, wr[r][k].y, vr[r][k].y);
            o.z = fmaf(tc, wr[r][k].z, vr[r][k].z);
            o.w = fmaf(tc, wr[r][k].w, vr[r][k].w);
            __builtin_nontemporal_store(o, o4 + l + (k << 6));
        }
        if (l == 0) {
            const float s      = fmaf(coef, w2_s[r], wu);
            const float inner2 = fmaf(th_s[r], s, in_s[r]);
            const float th2    = tanhf(inner2);
            const float hp     = 1.f - th2 * th2;
            ldout[row] = logf(fabsf(fmaf(hp, s, 1.f)));
        }
    }
}

extern "C" void kernel_launch(void* const* d_in, const int* in_sizes, int n_in,
                              void* d_out, int out_size, void* d_ws, size_t ws_size,
                              hipStream_t stream) {
    const float* z = (const float*)d_in[0];
    const float* w = (const float*)d_in[1];
    const float* u = (const float*)d_in[2];
    const float* b = (const float*)d_in[3];

    float* out   = (float*)d_out;
    float* zout  = out;                    // [BS, D]
    float* ldout = out + (size_t)BS * D;   // [BS]

    u64*          slots = (u64*)d_ws;                    // [NBLK] {tag,val}
    unsigned int* epoch = (unsigned int*)(slots + NBLK); // [1]

    // Deterministic host-side occupancy gate (capture-safe query): the
    // 512-thread variant needs 2 blocks/CU co-resident for its barrier.
    int nb2 = 0;
    hipError_t err =
        hipOccupancyMaxActiveBlocksPerMultiprocessor(&nb2, planar512, 512, 0);
    if (err == hipSuccess && nb2 >= 2) {
        planar512<<<NBLK, 512, 0, stream>>>(z, w, u, b, zout, ldout,
                                            slots, epoch);
    } else {
        planar256<<<NBLK, 256, 0, stream>>>(z, w, u, b, zout, ldout,
                                            slots, epoch);
    }
}